// Round 1
// baseline (561.488 us; speedup 1.0000x reference)
//
#include <hip/hip_runtime.h>
#include <hip/hip_bf16.h>

#define N_NODES 50000
#define N_EDGES 800000
#define IN_F 128
#define OUT_F 128
#define TOPK 32

// ---------------------------------------------------------------------------
// Kernel 1: in-degree count (atomics on dst)
// ---------------------------------------------------------------------------
__global__ void deg_kernel(const int* __restrict__ dst, int* __restrict__ deg, int E) {
    int e = blockIdx.x * blockDim.x + threadIdx.x;
    if (e < E) atomicAdd(&deg[dst[e]], 1);
}

// ---------------------------------------------------------------------------
// Kernel 2: per-node dedup mask. Position k survives iff no j>k has the same
// column index (numpy fancy-assignment last-wins semantics).
// ---------------------------------------------------------------------------
__global__ void mask_kernel(const int* __restrict__ topk_idx, unsigned* __restrict__ mask, int n) {
    int node = blockIdx.x * blockDim.x + threadIdx.x;
    if (node >= n) return;
    int idx[TOPK];
#pragma unroll
    for (int k = 0; k < TOPK; ++k) idx[k] = topk_idx[node * TOPK + k];
    unsigned m = 0;
#pragma unroll
    for (int k = 0; k < TOPK; ++k) {
        bool win = true;
        for (int j = k + 1; j < TOPK; ++j)
            if (idx[j] == idx[k]) { win = false; break; }
        if (win) m |= (1u << k);
    }
    mask[node] = m;
}

// ---------------------------------------------------------------------------
// Kernel 3: edge scatter. One edge per 32 lanes; lane k handles topk slot k.
// agg[dst][col] += (1/deg[dst]) * topk_values[src][k]  for winning slots.
// ---------------------------------------------------------------------------
__global__ void edge_scatter_kernel(const int* __restrict__ src, const int* __restrict__ dst,
                                    const float* __restrict__ vals, const int* __restrict__ idxs,
                                    const int* __restrict__ deg, const unsigned* __restrict__ mask,
                                    float* __restrict__ agg, int E) {
    int t = blockIdx.x * blockDim.x + threadIdx.x;
    int e = t >> 5;
    int k = t & 31;
    if (e >= E) return;
    int s = src[e];
    int d = dst[e];
    unsigned m = mask[s];
    float w = 1.0f / (float)max(deg[d], 1);
    if (m & (1u << k)) {
        int c = idxs[s * TOPK + k];
        float v = vals[s * TOPK + k];
        atomicAdd(&agg[d * IN_F + c], w * v);
    }
}

// ---------------------------------------------------------------------------
// Kernel 4: fused epilogue GEMM
//   out[n][o] = sum_i feat[n][i]*W_self[i][o] + agg[n][i]*W_neigh[i][o] + b[o]
// Block = 128 threads (one output column each), ROWS rows per block.
// W reads are coalesced across threads; feat/agg broadcast from LDS.
// ---------------------------------------------------------------------------
#define ROWS 8
__global__ __launch_bounds__(128) void fused_gemm_kernel(
    const float* __restrict__ feat, const float* __restrict__ agg,
    const float* __restrict__ Ws, const float* __restrict__ Wn,
    const float* __restrict__ b, float* __restrict__ out, int n) {
    __shared__ float sf[ROWS][IN_F];
    __shared__ float sa[ROWS][IN_F];
    int row0 = blockIdx.x * ROWS;
    int o = threadIdx.x;  // 0..127

#pragma unroll
    for (int r = 0; r < ROWS; ++r) {
        int row = row0 + r;
        if (row < n) {
            sf[r][o] = feat[row * IN_F + o];
            sa[r][o] = agg[row * IN_F + o];
        } else {
            sf[r][o] = 0.0f;
            sa[r][o] = 0.0f;
        }
    }
    __syncthreads();

    float acc[ROWS];
#pragma unroll
    for (int r = 0; r < ROWS; ++r) acc[r] = 0.0f;

    for (int i = 0; i < IN_F; ++i) {
        float ws = Ws[i * OUT_F + o];
        float wn = Wn[i * OUT_F + o];
#pragma unroll
        for (int r = 0; r < ROWS; ++r)
            acc[r] += sf[r][i] * ws + sa[r][i] * wn;
    }

    float bb = b[o];
#pragma unroll
    for (int r = 0; r < ROWS; ++r) {
        int row = row0 + r;
        if (row < n) out[row * OUT_F + o] = acc[r] + bb;
    }
}

// ---------------------------------------------------------------------------
extern "C" void kernel_launch(void* const* d_in, const int* in_sizes, int n_in,
                              void* d_out, int out_size, void* d_ws, size_t ws_size,
                              hipStream_t stream) {
    const float* feat     = (const float*)d_in[0];
    const float* vals     = (const float*)d_in[1];
    const int*   idxs     = (const int*)d_in[2];
    const int*   src      = (const int*)d_in[3];
    const int*   dst      = (const int*)d_in[4];
    const float* W_self   = (const float*)d_in[5];
    const float* b_self   = (const float*)d_in[6];
    const float* W_neigh  = (const float*)d_in[7];
    float*       out      = (float*)d_out;

    const int n = N_NODES;
    const int E = N_EDGES;

    // Workspace layout: agg [N*128 f32] | deg [N i32] | mask [N u32]
    float*    agg  = (float*)d_ws;
    int*      deg  = (int*)((char*)d_ws + (size_t)n * IN_F * sizeof(float));
    unsigned* mask = (unsigned*)((char*)deg + (size_t)n * sizeof(int));

    // Zero agg + deg in one contiguous memset (they are adjacent).
    hipMemsetAsync(d_ws, 0, (size_t)n * (IN_F + 1) * sizeof(float), stream);

    deg_kernel<<<(E + 255) / 256, 256, 0, stream>>>(dst, deg, E);
    mask_kernel<<<(n + 255) / 256, 256, 0, stream>>>(idxs, mask, n);
    edge_scatter_kernel<<<(E * 32 + 255) / 256, 256, 0, stream>>>(src, dst, vals, idxs, deg, mask, agg, E);
    fused_gemm_kernel<<<(n + ROWS - 1) / ROWS, 128, 0, stream>>>(feat, agg, W_self, W_neigh, b_self, out, n);
}

// Round 2
// 519.531 us; speedup vs baseline: 1.0808x; 1.0808x over previous
//
#include <hip/hip_runtime.h>
#include <hip/hip_bf16.h>

#define N_NODES 50000
#define N_EDGES 800000
#define IN_F 128
#define OUT_F 128
#define TOPK 32

// ---------------------------------------------------------------------------
// Kernel 1: in-degree count (int atomics on dst)
// ---------------------------------------------------------------------------
__global__ void deg_kernel(const int* __restrict__ dst, int* __restrict__ deg, int E) {
    int e = blockIdx.x * blockDim.x + threadIdx.x;
    if (e < E) atomicAdd(&deg[dst[e]], 1);
}

// ---------------------------------------------------------------------------
// Kernel 2: per-node dedup mask (numpy fancy-assignment last-wins).
// ---------------------------------------------------------------------------
__global__ void mask_kernel(const int* __restrict__ topk_idx, unsigned* __restrict__ mask, int n) {
    int node = blockIdx.x * blockDim.x + threadIdx.x;
    if (node >= n) return;
    int idx[TOPK];
#pragma unroll
    for (int k = 0; k < TOPK; ++k) idx[k] = topk_idx[node * TOPK + k];
    unsigned m = 0;
#pragma unroll
    for (int k = 0; k < TOPK; ++k) {
        bool win = true;
        for (int j = k + 1; j < TOPK; ++j)
            if (idx[j] == idx[k]) { win = false; break; }
        if (win) m |= (1u << k);
    }
    mask[node] = m;
}

// ---------------------------------------------------------------------------
// Kernel 3: y = x_sparse @ W_neigh  (sparse rows: <=32 nnz each)
// One wave per node, float2 per lane (64*2 = 128 cols). W_neigh in LDS (64KB).
// ---------------------------------------------------------------------------
__global__ __launch_bounds__(256) void spmm_y_kernel(
    const float* __restrict__ vals, const int* __restrict__ idxs,
    const unsigned* __restrict__ mask, const float* __restrict__ Wn,
    float* __restrict__ y, int n) {
    __shared__ float wl[IN_F * OUT_F];
    for (int i = threadIdx.x; i < IN_F * OUT_F / 4; i += 256)
        ((float4*)wl)[i] = ((const float4*)Wn)[i];
    __syncthreads();

    int wave = (blockIdx.x * 256 + threadIdx.x) >> 6;
    int lane = threadIdx.x & 63;
    if (wave >= n) return;
    int node = wave;

    unsigned m = mask[node];
    const float* v = vals + node * TOPK;
    const int* id = idxs + node * TOPK;
    float2 acc = {0.f, 0.f};
#pragma unroll 4
    for (int k = 0; k < TOPK; ++k) {
        if (!(m & (1u << k))) continue;
        float vk = v[k];
        int ik = id[k];
        float2 w2 = *(const float2*)&wl[ik * OUT_F + 2 * lane];
        acc.x += vk * w2.x;
        acc.y += vk * w2.y;
    }
    *(float2*)&y[node * OUT_F + 2 * lane] = acc;
}

// ---------------------------------------------------------------------------
// Kernel 4: single-block exclusive scan of deg -> off[0..n]
// ---------------------------------------------------------------------------
__global__ __launch_bounds__(1024) void scan_kernel(const int* __restrict__ deg,
                                                    int* __restrict__ off, int n) {
    __shared__ int partial[1024];
    int t = threadIdx.x;
    int chunk = (n + 1023) / 1024;
    int start = t * chunk;
    int end = min(start + chunk, n);
    int s = 0;
    for (int i = start; i < end; ++i) s += deg[i];
    partial[t] = s;
    __syncthreads();
    for (int d = 1; d < 1024; d <<= 1) {
        int v = (t >= d) ? partial[t - d] : 0;
        __syncthreads();
        partial[t] += v;
        __syncthreads();
    }
    int run = (t > 0) ? partial[t - 1] : 0;
    for (int i = start; i < end; ++i) { off[i] = run; run += deg[i]; }
    if (t == 1023) off[n] = run;
}

// ---------------------------------------------------------------------------
// Kernel 5: CSR scatter — esrc[off[d] + cursor[d]++] = src[e]
// ---------------------------------------------------------------------------
__global__ void csr_scatter_kernel(const int* __restrict__ src, const int* __restrict__ dst,
                                   const int* __restrict__ off, int* __restrict__ cursor,
                                   int* __restrict__ esrc, int E) {
    int e = blockIdx.x * blockDim.x + threadIdx.x;
    if (e >= E) return;
    int d = dst[e];
    int pos = off[d] + atomicAdd(&cursor[d], 1);
    esrc[pos] = src[e];
}

// ---------------------------------------------------------------------------
// Kernel 6: h_neigh[d] = (1/deg_d) * sum_{e in CSR[d]} y[src_e]   -> out
// One wave per dst node; dense coalesced 512B row gathers; NO fp atomics.
// ---------------------------------------------------------------------------
__global__ __launch_bounds__(256) void agg_kernel(const int* __restrict__ off,
                                                  const int* __restrict__ esrc,
                                                  const float* __restrict__ y,
                                                  float* __restrict__ out, int n) {
    int wave = (blockIdx.x * 256 + threadIdx.x) >> 6;
    int lane = threadIdx.x & 63;
    if (wave >= n) return;
    int d = wave;
    int b = off[d], e = off[d + 1];
    float2 acc = {0.f, 0.f};
    int j = b;
    // unroll-by-2 for memory-level parallelism
    for (; j + 1 < e; j += 2) {
        int s0 = esrc[j];
        int s1 = esrc[j + 1];
        float2 v0 = *(const float2*)&y[s0 * OUT_F + 2 * lane];
        float2 v1 = *(const float2*)&y[s1 * OUT_F + 2 * lane];
        acc.x += v0.x + v1.x;
        acc.y += v0.y + v1.y;
    }
    if (j < e) {
        int s0 = esrc[j];
        float2 v0 = *(const float2*)&y[s0 * OUT_F + 2 * lane];
        acc.x += v0.x;
        acc.y += v0.y;
    }
    float inv = 1.0f / (float)max(e - b, 1);
    acc.x *= inv;
    acc.y *= inv;
    *(float2*)&out[d * OUT_F + 2 * lane] = acc;
}

// ---------------------------------------------------------------------------
// Kernel 7: out += feat @ W_self + b   (out already holds h_neigh)
// ---------------------------------------------------------------------------
#define ROWS 8
__global__ __launch_bounds__(128) void gemm_self_kernel(
    const float* __restrict__ feat, const float* __restrict__ Ws,
    const float* __restrict__ b, float* __restrict__ out, int n) {
    __shared__ float sf[ROWS][IN_F];
    int row0 = blockIdx.x * ROWS;
    int o = threadIdx.x;  // 0..127

#pragma unroll
    for (int r = 0; r < ROWS; ++r) {
        int row = row0 + r;
        sf[r][o] = (row < n) ? feat[row * IN_F + o] : 0.0f;
    }
    __syncthreads();

    float acc[ROWS];
#pragma unroll
    for (int r = 0; r < ROWS; ++r) acc[r] = 0.0f;

    for (int i = 0; i < IN_F; ++i) {
        float ws = Ws[i * OUT_F + o];
#pragma unroll
        for (int r = 0; r < ROWS; ++r)
            acc[r] += sf[r][i] * ws;
    }

    float bb = b[o];
#pragma unroll
    for (int r = 0; r < ROWS; ++r) {
        int row = row0 + r;
        if (row < n) out[row * OUT_F + o] += acc[r] + bb;
    }
}

// ---------------------------------------------------------------------------
extern "C" void kernel_launch(void* const* d_in, const int* in_sizes, int n_in,
                              void* d_out, int out_size, void* d_ws, size_t ws_size,
                              hipStream_t stream) {
    const float* feat    = (const float*)d_in[0];
    const float* vals    = (const float*)d_in[1];
    const int*   idxs    = (const int*)d_in[2];
    const int*   src     = (const int*)d_in[3];
    const int*   dst     = (const int*)d_in[4];
    const float* W_self  = (const float*)d_in[5];
    const float* b_self  = (const float*)d_in[6];
    const float* W_neigh = (const float*)d_in[7];
    float*       out     = (float*)d_out;

    const int n = N_NODES;
    const int E = N_EDGES;

    // Workspace layout: [deg N][cursor N][y N*128][mask N][off N+1][esrc E]
    char* p = (char*)d_ws;
    int*      deg    = (int*)p;                 p += (size_t)n * sizeof(int);
    int*      cursor = (int*)p;                 p += (size_t)n * sizeof(int);
    float*    y      = (float*)p;               p += (size_t)n * IN_F * sizeof(float);
    unsigned* mask   = (unsigned*)p;            p += (size_t)n * sizeof(unsigned);
    int*      off    = (int*)p;                 p += (size_t)(n + 1) * sizeof(int);
    int*      esrc   = (int*)p;

    // Zero deg + cursor (adjacent) in one memset.
    hipMemsetAsync(d_ws, 0, 2ull * n * sizeof(int), stream);

    deg_kernel<<<(E + 255) / 256, 256, 0, stream>>>(dst, deg, E);
    mask_kernel<<<(n + 255) / 256, 256, 0, stream>>>(idxs, mask, n);
    spmm_y_kernel<<<(n + 3) / 4, 256, 0, stream>>>(vals, idxs, mask, W_neigh, y, n);
    scan_kernel<<<1, 1024, 0, stream>>>(deg, off, n);
    csr_scatter_kernel<<<(E + 255) / 256, 256, 0, stream>>>(src, dst, off, cursor, esrc, E);
    agg_kernel<<<(n * 64 + 255) / 256, 256, 0, stream>>>(off, esrc, y, out, n);
    gemm_self_kernel<<<(n + ROWS - 1) / ROWS, 128, 0, stream>>>(feat, W_self, b_self, out, n);
}

// Round 3
// 413.976 us; speedup vs baseline: 1.3563x; 1.2550x over previous
//
#include <hip/hip_runtime.h>
#include <hip/hip_bf16.h>

#define N_NODES 50000
#define N_EDGES 800000
#define IN_F 128
#define OUT_F 128
#define TOPK 32

// ---------------------------------------------------------------------------
// Kernel 1: in-degree count (int atomics on dst)
// ---------------------------------------------------------------------------
__global__ void deg_kernel(const int* __restrict__ dst, int* __restrict__ deg, int E) {
    int e = blockIdx.x * blockDim.x + threadIdx.x;
    if (e < E) atomicAdd(&deg[dst[e]], 1);
}

// ---------------------------------------------------------------------------
// Kernel 2: per-node dedup mask (numpy fancy-assignment last-wins).
// ---------------------------------------------------------------------------
__global__ void mask_kernel(const int* __restrict__ topk_idx, unsigned* __restrict__ mask, int n) {
    int node = blockIdx.x * blockDim.x + threadIdx.x;
    if (node >= n) return;
    int idx[TOPK];
#pragma unroll
    for (int k = 0; k < TOPK; ++k) idx[k] = topk_idx[node * TOPK + k];
    unsigned m = 0;
#pragma unroll
    for (int k = 0; k < TOPK; ++k) {
        bool win = true;
        for (int j = k + 1; j < TOPK; ++j)
            if (idx[j] == idx[k]) { win = false; break; }
        if (win) m |= (1u << k);
    }
    mask[node] = m;
}

// ---------------------------------------------------------------------------
// Kernel 3: y = x_sparse @ W_neigh. Persistent grid-stride waves; W_neigh
// staged in LDS ONCE per block and amortized over ~24 nodes per wave.
// Branchless inner loop (predicated zero) so all 32 loads pipeline.
// ---------------------------------------------------------------------------
#define SPMM_BLOCKS 512
__global__ __launch_bounds__(256) void spmm_y_kernel(
    const float* __restrict__ vals, const int* __restrict__ idxs,
    const unsigned* __restrict__ mask, const float* __restrict__ Wn,
    float* __restrict__ y, int n) {
    __shared__ float wl[IN_F * OUT_F];
    for (int i = threadIdx.x; i < IN_F * OUT_F / 4; i += 256)
        ((float4*)wl)[i] = ((const float4*)Wn)[i];
    __syncthreads();

    int wid = (blockIdx.x * 256 + threadIdx.x) >> 6;
    int lane = threadIdx.x & 63;
    int nwaves = SPMM_BLOCKS * 4;

    for (int node = wid; node < n; node += nwaves) {
        unsigned m = mask[node];
        const float* v = vals + node * TOPK;
        const int* id = idxs + node * TOPK;
        float2 acc = {0.f, 0.f};
#pragma unroll 8
        for (int k = 0; k < TOPK; ++k) {
            float vk = v[k];
            int ik = id[k];
            if (!((m >> k) & 1u)) vk = 0.f;  // predicated, loads stay unconditional
            float2 w2 = *(const float2*)&wl[ik * OUT_F + 2 * lane];
            acc.x += vk * w2.x;
            acc.y += vk * w2.y;
        }
        *(float2*)&y[node * OUT_F + 2 * lane] = acc;
    }
}

// ---------------------------------------------------------------------------
// Kernel 4: single-block exclusive scan of deg -> off[0..n]
// ---------------------------------------------------------------------------
__global__ __launch_bounds__(1024) void scan_kernel(const int* __restrict__ deg,
                                                    int* __restrict__ off, int n) {
    __shared__ int partial[1024];
    int t = threadIdx.x;
    int chunk = (n + 1023) / 1024;
    int start = t * chunk;
    int end = min(start + chunk, n);
    int s = 0;
    for (int i = start; i < end; ++i) s += deg[i];
    partial[t] = s;
    __syncthreads();
    for (int d = 1; d < 1024; d <<= 1) {
        int v = (t >= d) ? partial[t - d] : 0;
        __syncthreads();
        partial[t] += v;
        __syncthreads();
    }
    int run = (t > 0) ? partial[t - 1] : 0;
    for (int i = start; i < end; ++i) { off[i] = run; run += deg[i]; }
    if (t == 1023) off[n] = run;
}

// ---------------------------------------------------------------------------
// Kernel 5: CSR scatter — esrc[off[d] + cursor[d]++] = src[e]
// ---------------------------------------------------------------------------
__global__ void csr_scatter_kernel(const int* __restrict__ src, const int* __restrict__ dst,
                                   const int* __restrict__ off, int* __restrict__ cursor,
                                   int* __restrict__ esrc, int E) {
    int e = blockIdx.x * blockDim.x + threadIdx.x;
    if (e >= E) return;
    int d = dst[e];
    int pos = off[d] + atomicAdd(&cursor[d], 1);
    esrc[pos] = src[e];
}

// ---------------------------------------------------------------------------
// Kernel 6: h_neigh[d] = (1/deg_d) * sum_{e in CSR[d]} y[src_e]   -> out
// One wave per dst node; coalesced 512B row gathers; unroll-4 for MLP.
// ---------------------------------------------------------------------------
__global__ __launch_bounds__(256) void agg_kernel(const int* __restrict__ off,
                                                  const int* __restrict__ esrc,
                                                  const float* __restrict__ y,
                                                  float* __restrict__ out, int n) {
    int wave = (blockIdx.x * 256 + threadIdx.x) >> 6;
    int lane = threadIdx.x & 63;
    if (wave >= n) return;
    int d = wave;
    int b = off[d], e = off[d + 1];
    float2 acc = {0.f, 0.f};
    int j = b;
    for (; j + 3 < e; j += 4) {
        int s0 = esrc[j], s1 = esrc[j + 1], s2 = esrc[j + 2], s3 = esrc[j + 3];
        float2 v0 = *(const float2*)&y[s0 * OUT_F + 2 * lane];
        float2 v1 = *(const float2*)&y[s1 * OUT_F + 2 * lane];
        float2 v2 = *(const float2*)&y[s2 * OUT_F + 2 * lane];
        float2 v3 = *(const float2*)&y[s3 * OUT_F + 2 * lane];
        acc.x += (v0.x + v1.x) + (v2.x + v3.x);
        acc.y += (v0.y + v1.y) + (v2.y + v3.y);
    }
    for (; j < e; ++j) {
        int s0 = esrc[j];
        float2 v0 = *(const float2*)&y[s0 * OUT_F + 2 * lane];
        acc.x += v0.x;
        acc.y += v0.y;
    }
    float inv = 1.0f / (float)max(e - b, 1);
    acc.x *= inv;
    acc.y *= inv;
    *(float2*)&out[d * OUT_F + 2 * lane] = acc;
}

// ---------------------------------------------------------------------------
// Kernel 7: out += feat @ W_self + b   (out already holds h_neigh)
// ROWS=16 amortizes W traffic; i blocked by 4 -> ds_read_b128 for feat.
// ---------------------------------------------------------------------------
#define ROWS 16
__global__ __launch_bounds__(128) void gemm_self_kernel(
    const float* __restrict__ feat, const float* __restrict__ Ws,
    const float* __restrict__ b, float* __restrict__ out, int n) {
    __shared__ float sf[ROWS][IN_F];
    int row0 = blockIdx.x * ROWS;
    int o = threadIdx.x;  // 0..127

#pragma unroll
    for (int r = 0; r < ROWS; ++r) {
        int row = row0 + r;
        sf[r][o] = (row < n) ? feat[row * IN_F + o] : 0.0f;
    }
    __syncthreads();

    float acc[ROWS];
#pragma unroll
    for (int r = 0; r < ROWS; ++r) acc[r] = 0.0f;

    for (int i = 0; i < IN_F; i += 4) {
        float ws0 = Ws[(i + 0) * OUT_F + o];
        float ws1 = Ws[(i + 1) * OUT_F + o];
        float ws2 = Ws[(i + 2) * OUT_F + o];
        float ws3 = Ws[(i + 3) * OUT_F + o];
#pragma unroll
        for (int r = 0; r < ROWS; ++r) {
            float4 f = *(const float4*)&sf[r][i];
            acc[r] += f.x * ws0 + f.y * ws1 + f.z * ws2 + f.w * ws3;
        }
    }

    float bb = b[o];
#pragma unroll
    for (int r = 0; r < ROWS; ++r) {
        int row = row0 + r;
        if (row < n) out[row * OUT_F + o] += acc[r] + bb;
    }
}

// ---------------------------------------------------------------------------
extern "C" void kernel_launch(void* const* d_in, const int* in_sizes, int n_in,
                              void* d_out, int out_size, void* d_ws, size_t ws_size,
                              hipStream_t stream) {
    const float* feat    = (const float*)d_in[0];
    const float* vals    = (const float*)d_in[1];
    const int*   idxs    = (const int*)d_in[2];
    const int*   src     = (const int*)d_in[3];
    const int*   dst     = (const int*)d_in[4];
    const float* W_self  = (const float*)d_in[5];
    const float* b_self  = (const float*)d_in[6];
    const float* W_neigh = (const float*)d_in[7];
    float*       out     = (float*)d_out;

    const int n = N_NODES;
    const int E = N_EDGES;

    // Workspace layout: [deg N][cursor N][y N*128][mask N][off N+1][esrc E]
    char* p = (char*)d_ws;
    int*      deg    = (int*)p;                 p += (size_t)n * sizeof(int);
    int*      cursor = (int*)p;                 p += (size_t)n * sizeof(int);
    float*    y      = (float*)p;               p += (size_t)n * IN_F * sizeof(float);
    unsigned* mask   = (unsigned*)p;            p += (size_t)n * sizeof(unsigned);
    int*      off    = (int*)p;                 p += (size_t)(n + 1) * sizeof(int);
    int*      esrc   = (int*)p;

    // Zero deg + cursor (adjacent) in one memset.
    hipMemsetAsync(d_ws, 0, 2ull * n * sizeof(int), stream);

    deg_kernel<<<(E + 255) / 256, 256, 0, stream>>>(dst, deg, E);
    mask_kernel<<<(n + 255) / 256, 256, 0, stream>>>(idxs, mask, n);
    spmm_y_kernel<<<SPMM_BLOCKS, 256, 0, stream>>>(vals, idxs, mask, W_neigh, y, n);
    scan_kernel<<<1, 1024, 0, stream>>>(deg, off, n);
    csr_scatter_kernel<<<(E + 255) / 256, 256, 0, stream>>>(src, dst, off, cursor, esrc, E);
    agg_kernel<<<(n * 64 + 255) / 256, 256, 0, stream>>>(off, esrc, y, out, n);
    gemm_self_kernel<<<(n + ROWS - 1) / ROWS, 128, 0, stream>>>(feat, W_self, b_self, out, n);
}

// Round 4
// 399.503 us; speedup vs baseline: 1.4055x; 1.0362x over previous
//
#include <hip/hip_runtime.h>
#include <hip/hip_bf16.h>

#define N_NODES 50000
#define N_EDGES 800000
#define IN_F 128
#define OUT_F 128
#define TOPK 32

typedef __attribute__((ext_vector_type(8))) short short8;
typedef __attribute__((ext_vector_type(4))) float f32x4;

static __device__ inline unsigned short f2bf(float x) {
    __hip_bfloat16 h = __float2bfloat16(x);
    return *reinterpret_cast<unsigned short*>(&h);
}

// ---------------------------------------------------------------------------
// Kernel 1: fused in-degree count + dedup mask (last-wins semantics).
// ---------------------------------------------------------------------------
__global__ void deg_mask_kernel(const int* __restrict__ dst, int* __restrict__ deg,
                                const int* __restrict__ topk_idx, unsigned* __restrict__ mask,
                                int E, int n) {
    int t = blockIdx.x * blockDim.x + threadIdx.x;
    if (t < E) atomicAdd(&deg[dst[t]], 1);
    if (t < n) {
        int idx[TOPK];
#pragma unroll
        for (int k = 0; k < TOPK; ++k) idx[k] = topk_idx[t * TOPK + k];
        unsigned m = 0;
#pragma unroll
        for (int k = 0; k < TOPK; ++k) {
            bool win = true;
            for (int j = k + 1; j < TOPK; ++j)
                if (idx[j] == idx[k]) { win = false; break; }
            if (win) m |= (1u << k);
        }
        mask[t] = m;
    }
}

// ---------------------------------------------------------------------------
// Kernel 2: single-block exclusive scan of deg -> off[0..n]
// ---------------------------------------------------------------------------
__global__ __launch_bounds__(1024) void scan_kernel(const int* __restrict__ deg,
                                                    int* __restrict__ off, int n) {
    __shared__ int partial[1024];
    int t = threadIdx.x;
    int chunk = (n + 1023) / 1024;
    int start = t * chunk;
    int end = min(start + chunk, n);
    int s = 0;
    for (int i = start; i < end; ++i) s += deg[i];
    partial[t] = s;
    __syncthreads();
    for (int d = 1; d < 1024; d <<= 1) {
        int v = (t >= d) ? partial[t - d] : 0;
        __syncthreads();
        partial[t] += v;
        __syncthreads();
    }
    int run = (t > 0) ? partial[t - 1] : 0;
    for (int i = start; i < end; ++i) { off[i] = run; run += deg[i]; }
    if (t == 1023) off[n] = run;
}

// ---------------------------------------------------------------------------
// Kernel 3: CSR scatter — esrc[off[d] + cursor[d]++] = src[e]
// ---------------------------------------------------------------------------
__global__ void csr_scatter_kernel(const int* __restrict__ src, const int* __restrict__ dst,
                                   const int* __restrict__ off, int* __restrict__ cursor,
                                   int* __restrict__ esrc, int E) {
    int e = blockIdx.x * blockDim.x + threadIdx.x;
    if (e >= E) return;
    int d = dst[e];
    int pos = off[d] + atomicAdd(&cursor[d], 1);
    esrc[pos] = src[e];
}

// ---------------------------------------------------------------------------
// Kernel 4: x-space aggregation. One wave (=block) per dst node.
// LDS 128-float accumulator; per edge scatter <=32 (val,idx) pairs with
// LDS atomics (2 edges per iteration, half-wave each). Output bf16.
// Gather traffic: ~260B/edge from 13MB vals/idxs (L2-resident) vs 512B/edge
// from the old 25.6MB y buffer.
// ---------------------------------------------------------------------------
__global__ __launch_bounds__(64) void agg_x_kernel(
    const int* __restrict__ off, const int* __restrict__ esrc,
    const float* __restrict__ vals, const int* __restrict__ idxs,
    const unsigned* __restrict__ mask, unsigned short* __restrict__ agg_bf, int n) {
    __shared__ float acc[IN_F];
    int d = blockIdx.x;
    int l = threadIdx.x;
    acc[l] = 0.f;
    acc[l + 64] = 0.f;
    __syncthreads();
    int b = off[d], e = off[d + 1];
    int k = l & 31, half = l >> 5;
    for (int j = b; j < e; j += 2) {
        int jj = j + half;
        if (jj < e) {
            int s = esrc[jj];
            unsigned m = mask[s];
            float v = vals[s * TOPK + k];
            int c = idxs[s * TOPK + k];
            if ((m >> k) & 1u) atomicAdd(&acc[c], v);
        }
    }
    __syncthreads();
    float inv = 1.0f / (float)max(e - b, 1);
    __hip_bfloat162 h;
    h.x = __float2bfloat16(acc[2 * l] * inv);
    h.y = __float2bfloat16(acc[2 * l + 1] * inv);
    *(__hip_bfloat162*)&agg_bf[d * IN_F + 2 * l] = h;
}

// ---------------------------------------------------------------------------
// Kernel 5: fused MFMA GEMM:  out = [feat | agg] @ [Ws ; Wn] + b
// M=50000, N=128, K=256, bf16 MFMA 16x16x32.
// Block 256 thr = 4 waves; block tile 128 rows; wave = 2x16-row strips x 128 cols.
// B (weights) staged transposed [col][k] in LDS (pad to 264 bf16 -> 2-way-free
// bank pattern on ds_read_b128). A streamed from global (full-line coalesced).
// MFMA layouts (HW-verified per guide): A[m=lane&15][k=(lane>>4)*8+j],
// B[k=(lane>>4)*8+j][col=lane&15], C/D col=lane&15,row=(lane>>4)*4+reg.
// ---------------------------------------------------------------------------
#define BK_PAD 264
__global__ __launch_bounds__(256, 2) void fused_gemm_kernel(
    const float* __restrict__ feat, const unsigned short* __restrict__ agg_bf,
    const float* __restrict__ Ws, const float* __restrict__ Wn,
    const float* __restrict__ bias, float* __restrict__ out, int n) {
    __shared__ unsigned short BL[OUT_F * BK_PAD];  // 67.5 KB

    int t = threadIdx.x;
    // ---- stage B transposed: BL[col][k] = W[k][col] (bf16) ----
    {
        int col = t & 127;
        int khalf = t >> 7;  // 0: Ws (k<128), 1: Wn (k>=128)
        const float* W = khalf ? Wn : Ws;
        unsigned short* dstp = &BL[col * BK_PAD + khalf * 128];
#pragma unroll 4
        for (int kk = 0; kk < 128; kk += 2) {
            float w0 = W[kk * OUT_F + col];
            float w1 = W[(kk + 1) * OUT_F + col];
            unsigned v = (unsigned)f2bf(w0) | ((unsigned)f2bf(w1) << 16);
            *(unsigned*)&dstp[kk] = v;
        }
    }
    __syncthreads();

    int wave = t >> 6;
    int lane = t & 63;
    int quad = lane >> 4;
    int lq = lane & 15;
    int rowbase = blockIdx.x * 128 + wave * 32;
    int r0 = rowbase + lq;        // strip 0 A-row for this lane
    int r1 = rowbase + 16 + lq;   // strip 1

    f32x4 acc0[8], acc1[8];
#pragma unroll
    for (int i = 0; i < 8; ++i) { acc0[i] = (f32x4){0,0,0,0}; acc1[i] = (f32x4){0,0,0,0}; }

#pragma unroll
    for (int ks = 0; ks < 8; ++ks) {
        int k0 = ks * 32 + quad * 8;
        short8 a0, a1;
        if (ks < 4) {
            // feat half (fp32 -> bf16)
            float4 z = {0.f, 0.f, 0.f, 0.f};
            float4 f00 = (r0 < n) ? *(const float4*)&feat[r0 * IN_F + k0] : z;
            float4 f01 = (r0 < n) ? *(const float4*)&feat[r0 * IN_F + k0 + 4] : z;
            float4 f10 = (r1 < n) ? *(const float4*)&feat[r1 * IN_F + k0] : z;
            float4 f11 = (r1 < n) ? *(const float4*)&feat[r1 * IN_F + k0 + 4] : z;
            union { short8 s; unsigned short u[8]; } ua, ub;
            ua.u[0] = f2bf(f00.x); ua.u[1] = f2bf(f00.y); ua.u[2] = f2bf(f00.z); ua.u[3] = f2bf(f00.w);
            ua.u[4] = f2bf(f01.x); ua.u[5] = f2bf(f01.y); ua.u[6] = f2bf(f01.z); ua.u[7] = f2bf(f01.w);
            ub.u[0] = f2bf(f10.x); ub.u[1] = f2bf(f10.y); ub.u[2] = f2bf(f10.z); ub.u[3] = f2bf(f10.w);
            ub.u[4] = f2bf(f11.x); ub.u[5] = f2bf(f11.y); ub.u[6] = f2bf(f11.z); ub.u[7] = f2bf(f11.w);
            a0 = ua.s; a1 = ub.s;
        } else {
            int ka = k0 - 128;  // agg half (already bf16)
            short8 z = {0,0,0,0,0,0,0,0};
            a0 = (r0 < n) ? *(const short8*)&agg_bf[r0 * IN_F + ka] : z;
            a1 = (r1 < n) ? *(const short8*)&agg_bf[r1 * IN_F + ka] : z;
        }
#pragma unroll
        for (int nt = 0; nt < 8; ++nt) {
            short8 b = *(const short8*)&BL[(nt * 16 + lq) * BK_PAD + k0];
            acc0[nt] = __builtin_amdgcn_mfma_f32_16x16x32_bf16(a0, b, acc0[nt], 0, 0, 0);
            acc1[nt] = __builtin_amdgcn_mfma_f32_16x16x32_bf16(a1, b, acc1[nt], 0, 0, 0);
        }
    }

    // ---- epilogue: out[row][col] = acc + bias[col] ----
#pragma unroll
    for (int nt = 0; nt < 8; ++nt) {
        int col = nt * 16 + lq;
        float bb = bias[col];
#pragma unroll
        for (int r = 0; r < 4; ++r) {
            int row = rowbase + quad * 4 + r;
            if (row < n) out[row * OUT_F + col] = acc0[nt][r] + bb;
            int row2 = row + 16;
            if (row2 < n) out[row2 * OUT_F + col] = acc1[nt][r] + bb;
        }
    }
}

// ---------------------------------------------------------------------------
extern "C" void kernel_launch(void* const* d_in, const int* in_sizes, int n_in,
                              void* d_out, int out_size, void* d_ws, size_t ws_size,
                              hipStream_t stream) {
    const float* feat    = (const float*)d_in[0];
    const float* vals    = (const float*)d_in[1];
    const int*   idxs    = (const int*)d_in[2];
    const int*   src     = (const int*)d_in[3];
    const int*   dst     = (const int*)d_in[4];
    const float* W_self  = (const float*)d_in[5];
    const float* b_self  = (const float*)d_in[6];
    const float* W_neigh = (const float*)d_in[7];
    float*       out     = (float*)d_out;

    const int n = N_NODES;
    const int E = N_EDGES;

    // Workspace: [deg N][cursor N][mask N][off N+4 pad][esrc E][agg_bf N*128 u16]
    char* p = (char*)d_ws;
    int*            deg    = (int*)p;       p += (size_t)n * sizeof(int);
    int*            cursor = (int*)p;       p += (size_t)n * sizeof(int);
    unsigned*       mask   = (unsigned*)p;  p += (size_t)n * sizeof(unsigned);
    int*            off    = (int*)p;       p += (size_t)(n + 4) * sizeof(int);  // pad -> 16B align
    int*            esrc   = (int*)p;       p += (size_t)E * sizeof(int);
    unsigned short* agg_bf = (unsigned short*)p;

    hipMemsetAsync(d_ws, 0, 2ull * n * sizeof(int), stream);

    deg_mask_kernel<<<(E + 255) / 256, 256, 0, stream>>>(dst, deg, idxs, mask, E, n);
    scan_kernel<<<1, 1024, 0, stream>>>(deg, off, n);
    csr_scatter_kernel<<<(E + 255) / 256, 256, 0, stream>>>(src, dst, off, cursor, esrc, E);
    agg_x_kernel<<<n, 64, 0, stream>>>(off, esrc, vals, idxs, mask, agg_bf, n);
    fused_gemm_kernel<<<(n + 127) / 128, 256, 0, stream>>>(feat, agg_bf, W_self, W_neigh, b_self, out, n);
}